// Round 16
// baseline (117.308 us; speedup 1.0000x reference)
//
#include <hip/hip_runtime.h>
#include <hip/hip_bf16.h>

#define NJ 17
#define ROWS 32
#define TPB 256
#define TOKPB (ROWS * NJ)   // 544

#define LSJ 5
#define RSJ 6
#define LHJ 11
#define RHJ 12

// ws layout (u32 idx): [0,4096) W2 f16 image | [4096,6144) A1 frags
// [6144,6208) g1 f16 | [6208,6272) b1 f16 | [6272,6464) f32 g2,b2,p2b
#define WSU_A1   4096
#define WSU_PRM  6144

// sWS layout (u32 idx): [0,4096) W2 | [4096,4160) g1 | [4160,4224) b1
// [4224,4416) f32 g2,b2,p2b
#define SH_G1P  4096
#define SH_B1P  4160
#define SH_LN2  4224
#define SH_U32  4416

typedef __attribute__((ext_vector_type(8))) short bf16x8;
typedef __attribute__((ext_vector_type(8))) _Float16 f16x8;
typedef __attribute__((ext_vector_type(2))) _Float16 f16x2;
typedef __attribute__((ext_vector_type(4))) float f32x4;
typedef __attribute__((ext_vector_type(4))) unsigned int u32x4;

__device__ __forceinline__ unsigned short f2hu(float x) {
    _Float16 h = (_Float16)x;
    return __builtin_bit_cast(unsigned short, h);
}
__device__ __forceinline__ f16x2 cvt2h(float lo, float hi) {
    return __builtin_bit_cast(f16x2, __builtin_amdgcn_cvt_pkrtz(lo, hi));
}

// sum-reduce across a 16-lane row via DPP row rotates (VALU pipe, no LDS)
__device__ __forceinline__ float row16_sum(float s) {
    int t;
    t = __builtin_amdgcn_update_dpp(0, __builtin_bit_cast(int, s), 0x121, 0xf, 0xf, true);
    s += __builtin_bit_cast(float, t);
    t = __builtin_amdgcn_update_dpp(0, __builtin_bit_cast(int, s), 0x122, 0xf, 0xf, true);
    s += __builtin_bit_cast(float, t);
    t = __builtin_amdgcn_update_dpp(0, __builtin_bit_cast(int, s), 0x124, 0xf, 0xf, true);
    s += __builtin_bit_cast(float, t);
    t = __builtin_amdgcn_update_dpp(0, __builtin_bit_cast(int, s), 0x128, 0xf, 0xf, true);
    s += __builtin_bit_cast(float, t);
    return s;
}

__device__ __forceinline__ void norm_row(const float* __restrict__ r,
                                         float* __restrict__ ox,
                                         float* __restrict__ oy) {
    float sc0 = r[LSJ*3+2], sc1 = r[RSJ*3+2];
    float hc0 = r[LHJ*3+2], hc1 = r[RHJ*3+2];
    bool ut = ((sc0 > 0.f) || (sc1 > 0.f)) && ((hc0 > 0.f) || (hc1 > 0.f));

    float wl = sc0 > 0.f ? 1.f : 0.f;
    float wr = sc1 > 0.f ? 1.f : 0.f;
    float ws = fmaxf(wl + wr, 1.f);
    float smx = (wl * r[LSJ*3+0] + wr * r[RSJ*3+0]) / ws;
    float smy = (wl * r[LSJ*3+1] + wr * r[RSJ*3+1]) / ws;

    wl = hc0 > 0.f ? 1.f : 0.f;
    wr = hc1 > 0.f ? 1.f : 0.f;
    ws = fmaxf(wl + wr, 1.f);
    float hmx = (wl * r[LHJ*3+0] + wr * r[RHJ*3+0]) / ws;
    float hmy = (wl * r[LHJ*3+1] + wr * r[RHJ*3+1]) / ws;

    if (!ut) { smx = 0.f; smy = 0.f; hmx = 0.f; hmy = 0.f; }

    float cx = (smx + hmx) * 0.5f;
    float cy = (smy + hmy) * 0.5f;
    float dx = smx - hmx, dy = smy - hmy;
    float hh = sqrtf(dx * dx + dy * dy);
    bool valid = ut && (hh >= 10.0f);

    float mnx = r[0], mxx = r[0], mny = r[1], mxy = r[1];
    #pragma unroll
    for (int j = 1; j < NJ; ++j) {
        float x = r[j*3], y = r[j*3+1];
        mnx = fminf(mnx, x); mxx = fmaxf(mxx, x);
        mny = fminf(mny, y); mxy = fmaxf(mxy, y);
    }

    float ih  = 1.f / (hh + 1e-6f);
    float ibx = 1.f / (mxx - mnx + 1e-6f);
    float iby = 1.f / (mxy - mny + 1e-6f);

    #pragma unroll
    for (int j = 0; j < NJ; ++j) {
        float x = r[j*3], y = r[j*3+1];
        float tx = (x - cx) * ih, ty = (y - cy) * ih;
        float bx = (x - mnx) * ibx, by = (y - mny) * iby;
        float nx = valid ? tx : bx;
        float ny = valid ? ty : by;
        ox[j] = fminf(fmaxf(nx, -5.f), 5.f);
        oy[j] = fminf(fmaxf(ny, -5.f), 5.f);
    }
}

// ---------------- setup kernel: fold weights once into ws ----------------
__global__ __launch_bounds__(256) void setup_kernel(
    const float* __restrict__ emb,
    const float* __restrict__ posW, const float* __restrict__ posB,
    const float* __restrict__ velW, const float* __restrict__ velB,
    const float* __restrict__ angB,
    const float* __restrict__ relW, const float* __restrict__ relB,
    const float* __restrict__ confW, const float* __restrict__ confB,
    const float* __restrict__ P1, const float* __restrict__ p1b,
    const float* __restrict__ g1, const float* __restrict__ b1,
    const float* __restrict__ W2, const float* __restrict__ p2b,
    const float* __restrict__ g2, const float* __restrict__ b2,
    unsigned int* __restrict__ ws)
{
    __shared__ float sPA[7][128];
    __shared__ float sBase[128];
    __shared__ float sK0[17][128];
    const int tid = threadIdx.x;

    if (tid < 128) {
        const int n = tid;
        float pa0 = 0.f, pa1 = 0.f;
        #pragma unroll
        for (int i = 0; i < 16; ++i) {
            float w = P1[(16 + i) * 128 + n];
            pa0 += posW[i] * w; pa1 += posW[16 + i] * w;
        }
        float pv0 = 0.f, pv1 = 0.f;
        #pragma unroll
        for (int i = 0; i < 8; ++i) {
            float w = P1[(32 + i) * 128 + n];
            pv0 += velW[i] * w; pv1 += velW[8 + i] * w;
        }
        float pr0 = 0.f, pr1 = 0.f;
        #pragma unroll
        for (int i = 0; i < 8; ++i) {
            float w = P1[(48 + i) * 128 + n];
            pr0 += relW[i] * w; pr1 += relW[8 + i] * w;
        }
        float pc = 0.f;
        #pragma unroll
        for (int i = 0; i < 4; ++i) pc += confW[i] * P1[(56 + i) * 128 + n];

        float base = p1b[n];
        #pragma unroll
        for (int i = 0; i < 16; ++i) base += posB[i]  * P1[(16 + i) * 128 + n];
        #pragma unroll
        for (int i = 0; i < 8; ++i)  base += velB[i]  * P1[(32 + i) * 128 + n];
        #pragma unroll
        for (int i = 0; i < 8; ++i)  base += angB[i]  * P1[(40 + i) * 128 + n];
        #pragma unroll
        for (int i = 0; i < 8; ++i)  base += relB[i]  * P1[(48 + i) * 128 + n];
        #pragma unroll
        for (int i = 0; i < 4; ++i)  base += confB[i] * P1[(56 + i) * 128 + n];

        sPA[0][n] = pa0; sPA[1][n] = pa1;
        sPA[2][n] = pv0; sPA[3][n] = pv1;
        sPA[4][n] = pr0; sPA[5][n] = pr1;
        sPA[6][n] = pc;  sBase[n] = base;
    } else {
        // W2P swizzled f16 image (row = B-col source channel nt*16+tl)
        const int t = tid - 128;
        const int n = t & 63;
        const int gp = (t >> 6) * 2;
        const unsigned xm = (unsigned)(n & 15) << 4;
        #pragma unroll
        for (int dg = 0; dg < 2; ++dg) {
            const int gg = gp + dg;
            #pragma unroll
            for (int ks = 0; ks < 4; ++ks) {
                unsigned int pk[4];
                #pragma unroll
                for (int ep = 0; ep < 4; ++ep) {
                    int e0 = 2 * ep, e1 = 2 * ep + 1;
                    int c0 = 4 * gg + (e0 & 3) + 16 * (2 * ks + (e0 >> 2));
                    int c1 = 4 * gg + (e1 & 3) + 16 * (2 * ks + (e1 >> 2));
                    unsigned lo = f2hu(W2[c0 * 64 + n]);
                    unsigned hi = f2hu(W2[c1 * 64 + n]);
                    pk[ep] = lo | (hi << 16);
                }
                unsigned byte = (unsigned)n * 256u + ((unsigned)((ks * 4 + gg) * 16) ^ xm);
                *(u32x4*)&ws[byte >> 2] = (u32x4){pk[0], pk[1], pk[2], pk[3]};
            }
        }
    }

    // LN param packing (f16 pairs)
    if (tid < 32) {
        const int gg = tid >> 3, nt1 = tid & 7;
        const int c0 = 4 * gg + 16 * nt1;
        ws[WSU_PRM + tid * 2 + 0]      = (unsigned)f2hu(g1[c0+0]) | ((unsigned)f2hu(g1[c0+1]) << 16);
        ws[WSU_PRM + tid * 2 + 1]      = (unsigned)f2hu(g1[c0+2]) | ((unsigned)f2hu(g1[c0+3]) << 16);
        ws[WSU_PRM + 64 + tid * 2 + 0] = (unsigned)f2hu(b1[c0+0]) | ((unsigned)f2hu(b1[c0+1]) << 16);
        ws[WSU_PRM + 64 + tid * 2 + 1] = (unsigned)f2hu(b1[c0+2]) | ((unsigned)f2hu(b1[c0+3]) << 16);
    } else if (tid >= 64 && tid < 256) {
        const int i = tid - 64;   // 0..191
        float v = (i < 64) ? g2[i] : (i < 128 ? b2[i - 64] : p2b[i - 128]);
        ws[WSU_PRM + 128 + i] = __builtin_bit_cast(unsigned, v);
    }
    __syncthreads();

    // K0 table
    for (int e = tid; e < NJ * 128; e += 256) {
        int j = e >> 7, n = e & 127;
        float v = sBase[n];
        #pragma unroll
        for (int t = 0; t < 16; ++t) v += emb[j * 16 + t] * P1[t * 128 + n];
        sK0[j][n] = v;
    }
    __syncthreads();

    // A1 f16 fragments
    for (int i = tid; i < 512; i += 256) {
        const int nt1 = i >> 6, ln = i & 63, gg = ln >> 4, tl2 = ln & 15;
        const int ch = tl2 + 16 * nt1;
        float w[8];
        #pragma unroll
        for (int e = 0; e < 8; ++e) w[e] = 0.f;
        if (gg == 0) {
            #pragma unroll
            for (int e = 0; e < 7; ++e) w[e] = sPA[e][ch];
            w[7] = sK0[0][ch];
        } else if (gg == 1) {
            #pragma unroll
            for (int e = 0; e < 8; ++e) w[e] = sK0[e + 1][ch];
        } else if (gg == 2) {
            #pragma unroll
            for (int e = 0; e < 8; ++e) w[e] = sK0[e + 9][ch];
        }
        unsigned u[4];
        #pragma unroll
        for (int p = 0; p < 4; ++p) {
            unsigned short lo = f2hu(w[2*p]);
            unsigned short hi = f2hu(w[2*p+1]);
            u[p] = (unsigned)lo | ((unsigned)hi << 16);
        }
        *(u32x4*)&ws[WSU_A1 + i * 4] = (u32x4){u[0], u[1], u[2], u[3]};
    }
}

// ---------------- pipeline stages ----------------
__device__ __forceinline__ void front_tile(
    const int tbase, const int tl, const int g,
    const float4* __restrict__ sPk, const float2* __restrict__ sQ,
    const float2* __restrict__ sTc,
    const f16x8 (&a1f)[8], f32x4 (&acc1)[8])
{
    const int tok = tbase + tl;
    const int r = (tok * 3856) >> 16;      // tok/17 for tok<4096
    const int j = tok - r * NJ;

    const float4 pk = sPk[tok];
    const float2 qv = sQ[tok];
    const float2 tc = sTc[r];
    const float px = pk.x, py = pk.y, cf = pk.z;
    const float vx = px - qv.x, vy = py - qv.y;
    const float rx = px - tc.x, ry = py - tc.y;

    f16x8 bf;
    const int base7 = g * 8 - 7;
    #pragma unroll
    for (int e = 0; e < 8; ++e) {
        float oh = ((base7 + e) == j) ? 1.f : 0.f;
        float val;
        if (e == 0) val = (g == 0) ? px : oh;
        else if (e == 1) val = (g == 0) ? py : oh;
        else if (e == 2) val = (g == 0) ? vx : oh;
        else if (e == 3) val = (g == 0) ? vy : oh;
        else if (e == 4) val = (g == 0) ? rx : oh;
        else if (e == 5) val = (g == 0) ? ry : oh;
        else if (e == 6) val = (g == 0) ? cf : oh;
        else val = oh;
        bf[e] = (_Float16)val;
    }

    #pragma unroll
    for (int nt1 = 0; nt1 < 8; ++nt1)
        acc1[nt1] = __builtin_amdgcn_mfma_f32_16x16x32_f16(
            a1f[nt1], bf, (f32x4){0.f, 0.f, 0.f, 0.f}, 0, 0, 0);
}

__device__ __forceinline__ void back_tile(
    const int tbase, const int tl, const int g, const unsigned xm,
    const long long tok0, const long long ntok, const bool full,
    const unsigned int* __restrict__ sWS, float* __restrict__ sXp,
    const f16x2 (&g1h)[8][2], const f16x2 (&b1h)[8][2],
    const float (&g2v)[4], const float (&b2v)[4], const float (&p2v)[4],
    const f32x4 (&acc1)[8], float* __restrict__ out)
{
    // LN1 stats: tree reduction
    float s, ss;
    {
        float t0[8], t1[8];
        #pragma unroll
        for (int n1 = 0; n1 < 8; ++n1) {
            float a0 = acc1[n1][0], a1 = acc1[n1][1];
            float a2 = acc1[n1][2], a3 = acc1[n1][3];
            t0[n1] = (a0 + a1) + (a2 + a3);
            t1[n1] = (a0 * a0 + a1 * a1) + (a2 * a2 + a3 * a3);
        }
        s  = ((t0[0] + t0[1]) + (t0[2] + t0[3])) + ((t0[4] + t0[5]) + (t0[6] + t0[7]));
        ss = ((t1[0] + t1[1]) + (t1[2] + t1[3])) + ((t1[4] + t1[5]) + (t1[6] + t1[7]));
    }
    s += __shfl_xor(s, 16); ss += __shfl_xor(ss, 16);
    s += __shfl_xor(s, 32); ss += __shfl_xor(ss, 32);
    const float mu  = s * (1.f / 128.f);
    const float inv = rsqrtf(ss * (1.f / 128.f) - mu * mu + 1e-5f);

    // LN1 apply + relu in packed f16
    const f16x2 im2 = cvt2h(inv, inv);
    const f16x2 nm2 = cvt2h(-mu * inv, -mu * inv);
    const f16x2 zero2 = (f16x2)(_Float16)0.f;
    u32x4 afu[4];
    #pragma unroll
    for (int nt1 = 0; nt1 < 8; ++nt1) {
        const int ks = nt1 >> 1, sl = 2 * (nt1 & 1);
        f16x2 a01 = cvt2h(acc1[nt1][0], acc1[nt1][1]);
        f16x2 a23 = cvt2h(acc1[nt1][2], acc1[nt1][3]);
        f16x2 s01 = g1h[nt1][0] * im2;
        f16x2 s23 = g1h[nt1][1] * im2;
        f16x2 c01 = g1h[nt1][0] * nm2 + b1h[nt1][0];
        f16x2 c23 = g1h[nt1][1] * nm2 + b1h[nt1][1];
        f16x2 t01 = __builtin_elementwise_max(a01 * s01 + c01, zero2);
        f16x2 t23 = __builtin_elementwise_max(a23 * s23 + c23, zero2);
        afu[ks][sl + 0] = __builtin_bit_cast(unsigned, t01);
        afu[ks][sl + 1] = __builtin_bit_cast(unsigned, t23);
    }

    // matmul2 (f16): B from swizzled LDS
    f32x4 acc2[4];
    #pragma unroll
    for (int nt = 0; nt < 4; ++nt)
        acc2[nt] = (f32x4){p2v[nt], p2v[nt], p2v[nt], p2v[nt]};
    #pragma unroll
    for (int ks = 0; ks < 4; ++ks) {
        const unsigned so = ((unsigned)((ks * 4 + g) * 16) ^ xm) >> 2;
        const f16x8 afk = __builtin_bit_cast(f16x8, afu[ks]);
        #pragma unroll
        for (int nt = 0; nt < 4; ++nt) {
            const unsigned idx = (unsigned)(nt * 16 + tl) * 64u + so;
            f16x8 bw = __builtin_bit_cast(f16x8, *(const u32x4*)&sWS[idx]);
            acc2[nt] = __builtin_amdgcn_mfma_f32_16x16x32_f16(afk, bw, acc2[nt], 0, 0, 0);
        }
    }

    // LN2 stats for all q first, then pipelined transpose + store (fma form)
    float vi[4], nvi[4];
    #pragma unroll
    for (int q = 0; q < 4; ++q) {
        float a0 = acc2[0][q], a1 = acc2[1][q], a2 = acc2[2][q], a3 = acc2[3][q];
        float s2 = row16_sum((a0 + a1) + (a2 + a3));
        float q2 = row16_sum((a0 * a0 + a1 * a1) + (a2 * a2 + a3 * a3));
        float m = s2 * (1.f / 64.f);
        vi[q]  = rsqrtf(q2 * (1.f / 64.f) - m * m + 1e-5f);
        nvi[q] = -m * vi[q];
    }
    float* const obase = out + (((long long)(tok0 + tbase) + g * 4) << 6) + 4 * tl;

#define WRQ(q, rr) { \
    float* d = sXp + (rr) * 68; \
    d[ 0 + tl] = acc2[0][q] * vi[q] + nvi[q]; \
    d[16 + tl] = acc2[1][q] * vi[q] + nvi[q]; \
    d[32 + tl] = acc2[2][q] * vi[q] + nvi[q]; \
    d[48 + tl] = acc2[3][q] * vi[q] + nvi[q]; }
#define RDQ(q, rr) { \
    f32x4 w = *(const f32x4*)&sXp[(rr) * 68 + 4 * tl]; \
    f32x4 v; \
    v[0] = w[0] * g2v[0] + b2v[0]; v[1] = w[1] * g2v[1] + b2v[1]; \
    v[2] = w[2] * g2v[2] + b2v[2]; v[3] = w[3] * g2v[3] + b2v[3]; \
    *(f32x4*)(obase + (q) * 64) = v; }
#define RDQG(q, rr) { \
    if (tok0 + tbase + g * 4 + (q) < ntok) RDQ(q, rr) }

    if (full) {
        WRQ(0, 0); WRQ(1, 1); RDQ(0, 0);
        WRQ(2, 0); RDQ(1, 1);
        WRQ(3, 1); RDQ(2, 0); RDQ(3, 1);
    } else {
        WRQ(0, 0); WRQ(1, 1); RDQG(0, 0);
        WRQ(2, 0); RDQG(1, 1);
        WRQ(3, 1); RDQG(2, 0); RDQG(3, 1);
    }
#undef WRQ
#undef RDQ
#undef RDQG
}

// ---------------- main kernel ----------------
__global__ __launch_bounds__(TPB, 2)
void jfe_kernel(
    const float* __restrict__ kp, const float* __restrict__ pkp,
    const unsigned int* __restrict__ ws,
    float* __restrict__ out, int B)
{
    __shared__ __align__(16) unsigned int sWS[SH_U32];   // 17664 B (W2 + params)
    __shared__ __align__(16) unsigned int sA1[2176];     // 8704 B (A1 frags -> sXp)
    __shared__ __align__(16) float4 sPk[TOKPB];
    __shared__ __align__(8)  float2 sQ[TOKPB];
    __shared__ float2 sTc[ROWS];

    const int tid  = threadIdx.x;
    const int lane = tid & 63;
    const int wv   = tid >> 6;
    const int g    = lane >> 4;
    const int tl   = lane & 15;

    const int row0  = blockIdx.x * ROWS;
    const int nrows = min(ROWS, B - row0);
    const long long tok0 = (long long)blockIdx.x * TOKPB;
    const long long ntok = (long long)B * NJ;

    // ---- stage all block-invariant data ws -> LDS ----
    for (int c = tid; c < 1024; c += TPB)
        *(u32x4*)&sWS[c * 4] = *(const u32x4*)&ws[c * 4];
    for (int c = tid; c < 512; c += TPB)
        *(u32x4*)&sA1[c * 4] = *(const u32x4*)&ws[WSU_A1 + c * 4];
    if (tid < 80)
        *(u32x4*)&sWS[SH_G1P + tid * 4] = *(const u32x4*)&ws[WSU_PRM + tid * 4];

    // ---- normalization: 64 tasks spread across all 4 waves ----
    if (tl < 16 && g == 0) {
        const int task  = wv * 16 + tl;
        const int frame = task >> 5;
        const int row   = task & 31;
        if (row < nrows) {
            float ox[NJ], oy[NJ];
            if (frame == 0) {
                const float* rp = kp + (long long)(row0 + row) * 51;
                norm_row(rp, ox, oy);
                #pragma unroll
                for (int j = 0; j < NJ; ++j)
                    sPk[row * NJ + j] = make_float4(ox[j], oy[j], rp[j * 3 + 2], 0.f);
                sTc[row] = make_float2(
                    0.25f * (ox[LSJ] + ox[RSJ] + ox[LHJ] + ox[RHJ]),
                    0.25f * (oy[LSJ] + oy[RSJ] + oy[LHJ] + oy[RHJ]));
            } else {
                norm_row(pkp + (long long)(row0 + row) * 51, ox, oy);
                #pragma unroll
                for (int j = 0; j < NJ; ++j)
                    sQ[row * NJ + j] = make_float2(ox[j], oy[j]);
            }
        }
    }
    __syncthreads();

    // ---- preload per-lane constants from LDS ----
    f16x8 a1f[8];
    #pragma unroll
    for (int nt1 = 0; nt1 < 8; ++nt1)
        a1f[nt1] = __builtin_bit_cast(f16x8,
            *(const u32x4*)&sA1[(nt1 * 64 + lane) * 4]);

    f16x2 g1h[8][2], b1h[8][2];
    #pragma unroll
    for (int nt1 = 0; nt1 < 8; ++nt1) {
        g1h[nt1][0] = __builtin_bit_cast(f16x2, sWS[SH_G1P + (g * 8 + nt1) * 2 + 0]);
        g1h[nt1][1] = __builtin_bit_cast(f16x2, sWS[SH_G1P + (g * 8 + nt1) * 2 + 1]);
        b1h[nt1][0] = __builtin_bit_cast(f16x2, sWS[SH_B1P + (g * 8 + nt1) * 2 + 0]);
        b1h[nt1][1] = __builtin_bit_cast(f16x2, sWS[SH_B1P + (g * 8 + nt1) * 2 + 1]);
    }
    float g2v[4], b2v[4], p2v[4];
    #pragma unroll
    for (int nt = 0; nt < 4; ++nt) {
        g2v[nt] = __builtin_bit_cast(float, sWS[SH_LN2 +   0 + 4 * tl + nt]);
        b2v[nt] = __builtin_bit_cast(float, sWS[SH_LN2 +  64 + 4 * tl + nt]);
        p2v[nt] = __builtin_bit_cast(float, sWS[SH_LN2 + 128 + nt * 16 + tl]);
    }
    __syncthreads();   // all waves' a1f preloads done before sA1 reused as sXp

    float* const sXp = (float*)sA1 + wv * 544 + g * 136;

    const bool full = (nrows == ROWS);
    const int ntiles = (nrows * NJ + 15) >> 4;
    const unsigned xm = (unsigned)tl << 4;

    // ---- 2-stage software pipeline: front(t+4) overlaps back(t) ----
    f32x4 accA[8], accB[8];
    int t = wv;                       // wv < 4 <= ntiles always
    front_tile(t * 16, tl, g, sPk, sQ, sTc, a1f, accA);
    while (true) {
        if (t + 4 < ntiles)
            front_tile((t + 4) * 16, tl, g, sPk, sQ, sTc, a1f, accB);
        back_tile(t * 16, tl, g, xm, tok0, ntok, full, sWS, sXp,
                  g1h, b1h, g2v, b2v, p2v, accA, out);
        t += 4;
        if (t >= ntiles) break;

        if (t + 4 < ntiles)
            front_tile((t + 4) * 16, tl, g, sPk, sQ, sTc, a1f, accA);
        back_tile(t * 16, tl, g, xm, tok0, ntok, full, sWS, sXp,
                  g1h, b1h, g2v, b2v, p2v, accB, out);
        t += 4;
        if (t >= ntiles) break;
    }
}

extern "C" void kernel_launch(void* const* d_in, const int* in_sizes, int n_in,
                              void* d_out, int out_size, void* d_ws, size_t ws_size,
                              hipStream_t stream) {
    const float* kp    = (const float*)d_in[0];
    const float* pkp   = (const float*)d_in[1];
    const float* emb   = (const float*)d_in[2];
    const float* posW  = (const float*)d_in[3];
    const float* posB  = (const float*)d_in[4];
    const float* velW  = (const float*)d_in[5];
    const float* velB  = (const float*)d_in[6];
    const float* angB  = (const float*)d_in[8];
    const float* relW  = (const float*)d_in[9];
    const float* relB  = (const float*)d_in[10];
    const float* confW = (const float*)d_in[11];
    const float* confB = (const float*)d_in[12];
    const float* P1    = (const float*)d_in[13];
    const float* p1b   = (const float*)d_in[14];
    const float* g1    = (const float*)d_in[15];
    const float* b1    = (const float*)d_in[16];
    const float* W2    = (const float*)d_in[17];
    const float* p2b   = (const float*)d_in[18];
    const float* g2    = (const float*)d_in[19];
    const float* b2    = (const float*)d_in[20];
    float* out = (float*)d_out;
    unsigned int* ws = (unsigned int*)d_ws;

    int B = in_sizes[0] / (NJ * 3);

    setup_kernel<<<1, 256, 0, stream>>>(
        emb, posW, posB, velW, velB, angB, relW, relB, confW, confB,
        P1, p1b, g1, b1, W2, p2b, g2, b2, ws);

    int nblocks = (B + ROWS - 1) / ROWS;
    jfe_kernel<<<nblocks, TPB, 0, stream>>>(kp, pkp, ws, out, B);
}

// Round 17
// 85.454 us; speedup vs baseline: 1.3728x; 1.3728x over previous
//
#include <hip/hip_runtime.h>
#include <hip/hip_bf16.h>

#define NJ 17
#define ROWS 32
#define TPB 256
#define TOKPB (ROWS * NJ)   // 544

#define LSJ 5
#define RSJ 6
#define LHJ 11
#define RHJ 12

// ws layout (u32 idx): [0,4096) W2 f16 image | [4096,6144) A1 frags
// [6144,6208) g1 f16 | [6208,6272) b1 f16 | [6272,6464) f32 g2,b2,p2b
#define WSU_A1   4096
#define WSU_PRM  6144

// sWS layout (u32 idx): [0,4096) W2 | [4096,4160) g1 | [4160,4224) b1
// [4224,4416) f32 g2,b2,p2b
#define SH_G1P  4096
#define SH_B1P  4160
#define SH_LN2  4224
#define SH_U32  4416

typedef __attribute__((ext_vector_type(8))) short bf16x8;
typedef __attribute__((ext_vector_type(8))) _Float16 f16x8;
typedef __attribute__((ext_vector_type(2))) _Float16 f16x2;
typedef __attribute__((ext_vector_type(4))) float f32x4;
typedef __attribute__((ext_vector_type(4))) unsigned int u32x4;

__device__ __forceinline__ unsigned short f2hu(float x) {
    _Float16 h = (_Float16)x;
    return __builtin_bit_cast(unsigned short, h);
}
__device__ __forceinline__ f16x2 cvt2h(float lo, float hi) {
    return __builtin_bit_cast(f16x2, __builtin_amdgcn_cvt_pkrtz(lo, hi));
}

// sum-reduce across a 16-lane row via DPP row rotates (VALU pipe, no LDS)
__device__ __forceinline__ float row16_sum(float s) {
    int t;
    t = __builtin_amdgcn_update_dpp(0, __builtin_bit_cast(int, s), 0x121, 0xf, 0xf, true);
    s += __builtin_bit_cast(float, t);
    t = __builtin_amdgcn_update_dpp(0, __builtin_bit_cast(int, s), 0x122, 0xf, 0xf, true);
    s += __builtin_bit_cast(float, t);
    t = __builtin_amdgcn_update_dpp(0, __builtin_bit_cast(int, s), 0x124, 0xf, 0xf, true);
    s += __builtin_bit_cast(float, t);
    t = __builtin_amdgcn_update_dpp(0, __builtin_bit_cast(int, s), 0x128, 0xf, 0xf, true);
    s += __builtin_bit_cast(float, t);
    return s;
}

__device__ __forceinline__ void norm_row(const float* __restrict__ r,
                                         float* __restrict__ ox,
                                         float* __restrict__ oy) {
    float sc0 = r[LSJ*3+2], sc1 = r[RSJ*3+2];
    float hc0 = r[LHJ*3+2], hc1 = r[RHJ*3+2];
    bool ut = ((sc0 > 0.f) || (sc1 > 0.f)) && ((hc0 > 0.f) || (hc1 > 0.f));

    float wl = sc0 > 0.f ? 1.f : 0.f;
    float wr = sc1 > 0.f ? 1.f : 0.f;
    float ws = fmaxf(wl + wr, 1.f);
    float smx = (wl * r[LSJ*3+0] + wr * r[RSJ*3+0]) / ws;
    float smy = (wl * r[LSJ*3+1] + wr * r[RSJ*3+1]) / ws;

    wl = hc0 > 0.f ? 1.f : 0.f;
    wr = hc1 > 0.f ? 1.f : 0.f;
    ws = fmaxf(wl + wr, 1.f);
    float hmx = (wl * r[LHJ*3+0] + wr * r[RHJ*3+0]) / ws;
    float hmy = (wl * r[LHJ*3+1] + wr * r[RHJ*3+1]) / ws;

    if (!ut) { smx = 0.f; smy = 0.f; hmx = 0.f; hmy = 0.f; }

    float cx = (smx + hmx) * 0.5f;
    float cy = (smy + hmy) * 0.5f;
    float dx = smx - hmx, dy = smy - hmy;
    float hh = sqrtf(dx * dx + dy * dy);
    bool valid = ut && (hh >= 10.0f);

    float mnx = r[0], mxx = r[0], mny = r[1], mxy = r[1];
    #pragma unroll
    for (int j = 1; j < NJ; ++j) {
        float x = r[j*3], y = r[j*3+1];
        mnx = fminf(mnx, x); mxx = fmaxf(mxx, x);
        mny = fminf(mny, y); mxy = fmaxf(mxy, y);
    }

    float ih  = 1.f / (hh + 1e-6f);
    float ibx = 1.f / (mxx - mnx + 1e-6f);
    float iby = 1.f / (mxy - mny + 1e-6f);

    #pragma unroll
    for (int j = 0; j < NJ; ++j) {
        float x = r[j*3], y = r[j*3+1];
        float tx = (x - cx) * ih, ty = (y - cy) * ih;
        float bx = (x - mnx) * ibx, by = (y - mny) * iby;
        float nx = valid ? tx : bx;
        float ny = valid ? ty : by;
        ox[j] = fminf(fmaxf(nx, -5.f), 5.f);
        oy[j] = fminf(fmaxf(ny, -5.f), 5.f);
    }
}

// ---------------- setup kernel: fold weights once into ws ----------------
__global__ __launch_bounds__(256) void setup_kernel(
    const float* __restrict__ emb,
    const float* __restrict__ posW, const float* __restrict__ posB,
    const float* __restrict__ velW, const float* __restrict__ velB,
    const float* __restrict__ angB,
    const float* __restrict__ relW, const float* __restrict__ relB,
    const float* __restrict__ confW, const float* __restrict__ confB,
    const float* __restrict__ P1, const float* __restrict__ p1b,
    const float* __restrict__ g1, const float* __restrict__ b1,
    const float* __restrict__ W2, const float* __restrict__ p2b,
    const float* __restrict__ g2, const float* __restrict__ b2,
    unsigned int* __restrict__ ws)
{
    __shared__ float sPA[7][128];
    __shared__ float sBase[128];
    __shared__ float sK0[17][128];
    const int tid = threadIdx.x;

    if (tid < 128) {
        const int n = tid;
        float pa0 = 0.f, pa1 = 0.f;
        #pragma unroll
        for (int i = 0; i < 16; ++i) {
            float w = P1[(16 + i) * 128 + n];
            pa0 += posW[i] * w; pa1 += posW[16 + i] * w;
        }
        float pv0 = 0.f, pv1 = 0.f;
        #pragma unroll
        for (int i = 0; i < 8; ++i) {
            float w = P1[(32 + i) * 128 + n];
            pv0 += velW[i] * w; pv1 += velW[8 + i] * w;
        }
        float pr0 = 0.f, pr1 = 0.f;
        #pragma unroll
        for (int i = 0; i < 8; ++i) {
            float w = P1[(48 + i) * 128 + n];
            pr0 += relW[i] * w; pr1 += relW[8 + i] * w;
        }
        float pc = 0.f;
        #pragma unroll
        for (int i = 0; i < 4; ++i) pc += confW[i] * P1[(56 + i) * 128 + n];

        float base = p1b[n];
        #pragma unroll
        for (int i = 0; i < 16; ++i) base += posB[i]  * P1[(16 + i) * 128 + n];
        #pragma unroll
        for (int i = 0; i < 8; ++i)  base += velB[i]  * P1[(32 + i) * 128 + n];
        #pragma unroll
        for (int i = 0; i < 8; ++i)  base += angB[i]  * P1[(40 + i) * 128 + n];
        #pragma unroll
        for (int i = 0; i < 8; ++i)  base += relB[i]  * P1[(48 + i) * 128 + n];
        #pragma unroll
        for (int i = 0; i < 4; ++i)  base += confB[i] * P1[(56 + i) * 128 + n];

        sPA[0][n] = pa0; sPA[1][n] = pa1;
        sPA[2][n] = pv0; sPA[3][n] = pv1;
        sPA[4][n] = pr0; sPA[5][n] = pr1;
        sPA[6][n] = pc;  sBase[n] = base;
    } else {
        // W2P swizzled f16 image (row = B-col source channel nt*16+tl)
        const int t = tid - 128;
        const int n = t & 63;
        const int gp = (t >> 6) * 2;
        const unsigned xm = (unsigned)(n & 15) << 4;
        #pragma unroll
        for (int dg = 0; dg < 2; ++dg) {
            const int gg = gp + dg;
            #pragma unroll
            for (int ks = 0; ks < 4; ++ks) {
                unsigned int pk[4];
                #pragma unroll
                for (int ep = 0; ep < 4; ++ep) {
                    int e0 = 2 * ep, e1 = 2 * ep + 1;
                    int c0 = 4 * gg + (e0 & 3) + 16 * (2 * ks + (e0 >> 2));
                    int c1 = 4 * gg + (e1 & 3) + 16 * (2 * ks + (e1 >> 2));
                    unsigned lo = f2hu(W2[c0 * 64 + n]);
                    unsigned hi = f2hu(W2[c1 * 64 + n]);
                    pk[ep] = lo | (hi << 16);
                }
                unsigned byte = (unsigned)n * 256u + ((unsigned)((ks * 4 + gg) * 16) ^ xm);
                *(u32x4*)&ws[byte >> 2] = (u32x4){pk[0], pk[1], pk[2], pk[3]};
            }
        }
    }

    // LN param packing (f16 pairs)
    if (tid < 32) {
        const int gg = tid >> 3, nt1 = tid & 7;
        const int c0 = 4 * gg + 16 * nt1;
        ws[WSU_PRM + tid * 2 + 0]      = (unsigned)f2hu(g1[c0+0]) | ((unsigned)f2hu(g1[c0+1]) << 16);
        ws[WSU_PRM + tid * 2 + 1]      = (unsigned)f2hu(g1[c0+2]) | ((unsigned)f2hu(g1[c0+3]) << 16);
        ws[WSU_PRM + 64 + tid * 2 + 0] = (unsigned)f2hu(b1[c0+0]) | ((unsigned)f2hu(b1[c0+1]) << 16);
        ws[WSU_PRM + 64 + tid * 2 + 1] = (unsigned)f2hu(b1[c0+2]) | ((unsigned)f2hu(b1[c0+3]) << 16);
    } else if (tid >= 64 && tid < 256) {
        const int i = tid - 64;   // 0..191
        float v = (i < 64) ? g2[i] : (i < 128 ? b2[i - 64] : p2b[i - 128]);
        ws[WSU_PRM + 128 + i] = __builtin_bit_cast(unsigned, v);
    }
    __syncthreads();

    // K0 table
    for (int e = tid; e < NJ * 128; e += 256) {
        int j = e >> 7, n = e & 127;
        float v = sBase[n];
        #pragma unroll
        for (int t = 0; t < 16; ++t) v += emb[j * 16 + t] * P1[t * 128 + n];
        sK0[j][n] = v;
    }
    __syncthreads();

    // A1 f16 fragments
    for (int i = tid; i < 512; i += 256) {
        const int nt1 = i >> 6, ln = i & 63, gg = ln >> 4, tl2 = ln & 15;
        const int ch = tl2 + 16 * nt1;
        float w[8];
        #pragma unroll
        for (int e = 0; e < 8; ++e) w[e] = 0.f;
        if (gg == 0) {
            #pragma unroll
            for (int e = 0; e < 7; ++e) w[e] = sPA[e][ch];
            w[7] = sK0[0][ch];
        } else if (gg == 1) {
            #pragma unroll
            for (int e = 0; e < 8; ++e) w[e] = sK0[e + 1][ch];
        } else if (gg == 2) {
            #pragma unroll
            for (int e = 0; e < 8; ++e) w[e] = sK0[e + 9][ch];
        }
        unsigned u[4];
        #pragma unroll
        for (int p = 0; p < 4; ++p) {
            unsigned short lo = f2hu(w[2*p]);
            unsigned short hi = f2hu(w[2*p+1]);
            u[p] = (unsigned)lo | ((unsigned)hi << 16);
        }
        *(u32x4*)&ws[WSU_A1 + i * 4] = (u32x4){u[0], u[1], u[2], u[3]};
    }
}

// ---------------- pipeline stages ----------------
__device__ __forceinline__ void front_tile(
    const int tbase, const int tl, const int g,
    const float4* __restrict__ sPk, const float2* __restrict__ sQ,
    const float2* __restrict__ sTc,
    const f16x8 (&a1f)[8], f32x4 (&acc1)[8])
{
    const int tok = tbase + tl;
    const int r = (tok * 3856) >> 16;      // tok/17 for tok<4096
    const int j = tok - r * NJ;

    const float4 pk = sPk[tok];
    const float2 qv = sQ[tok];
    const float2 tc = sTc[r];
    const float px = pk.x, py = pk.y, cf = pk.z;
    const float vx = px - qv.x, vy = py - qv.y;
    const float rx = px - tc.x, ry = py - tc.y;

    f16x8 bf;
    const int base7 = g * 8 - 7;
    #pragma unroll
    for (int e = 0; e < 8; ++e) {
        float oh = ((base7 + e) == j) ? 1.f : 0.f;
        float val;
        if (e == 0) val = (g == 0) ? px : oh;
        else if (e == 1) val = (g == 0) ? py : oh;
        else if (e == 2) val = (g == 0) ? vx : oh;
        else if (e == 3) val = (g == 0) ? vy : oh;
        else if (e == 4) val = (g == 0) ? rx : oh;
        else if (e == 5) val = (g == 0) ? ry : oh;
        else if (e == 6) val = (g == 0) ? cf : oh;
        else val = oh;
        bf[e] = (_Float16)val;
    }

    #pragma unroll
    for (int nt1 = 0; nt1 < 8; ++nt1)
        acc1[nt1] = __builtin_amdgcn_mfma_f32_16x16x32_f16(
            a1f[nt1], bf, (f32x4){0.f, 0.f, 0.f, 0.f}, 0, 0, 0);
}

__device__ __forceinline__ void back_tile(
    const int tbase, const int tl, const int g, const unsigned xm,
    const long long tok0, const long long ntok, const bool full,
    const unsigned int* __restrict__ sWS, float* __restrict__ sXp,
    const f16x2 (&g1h)[8][2], const f16x2 (&b1h)[8][2],
    const float (&g2v)[4], const float (&b2v)[4], const float (&p2v)[4],
    const f32x4 (&acc1)[8], float* __restrict__ out)
{
    // LN1 stats: tree reduction
    float s, ss;
    {
        float t0[8], t1[8];
        #pragma unroll
        for (int n1 = 0; n1 < 8; ++n1) {
            float a0 = acc1[n1][0], a1 = acc1[n1][1];
            float a2 = acc1[n1][2], a3 = acc1[n1][3];
            t0[n1] = (a0 + a1) + (a2 + a3);
            t1[n1] = (a0 * a0 + a1 * a1) + (a2 * a2 + a3 * a3);
        }
        s  = ((t0[0] + t0[1]) + (t0[2] + t0[3])) + ((t0[4] + t0[5]) + (t0[6] + t0[7]));
        ss = ((t1[0] + t1[1]) + (t1[2] + t1[3])) + ((t1[4] + t1[5]) + (t1[6] + t1[7]));
    }
    s += __shfl_xor(s, 16); ss += __shfl_xor(ss, 16);
    s += __shfl_xor(s, 32); ss += __shfl_xor(ss, 32);
    const float mu  = s * (1.f / 128.f);
    const float inv = rsqrtf(ss * (1.f / 128.f) - mu * mu + 1e-5f);

    // LN1 apply + relu in packed f16
    const f16x2 im2 = cvt2h(inv, inv);
    const f16x2 nm2 = cvt2h(-mu * inv, -mu * inv);
    const f16x2 zero2 = (f16x2)(_Float16)0.f;
    u32x4 afu[4];
    #pragma unroll
    for (int nt1 = 0; nt1 < 8; ++nt1) {
        const int ks = nt1 >> 1, sl = 2 * (nt1 & 1);
        f16x2 a01 = cvt2h(acc1[nt1][0], acc1[nt1][1]);
        f16x2 a23 = cvt2h(acc1[nt1][2], acc1[nt1][3]);
        f16x2 s01 = g1h[nt1][0] * im2;
        f16x2 s23 = g1h[nt1][1] * im2;
        f16x2 c01 = g1h[nt1][0] * nm2 + b1h[nt1][0];
        f16x2 c23 = g1h[nt1][1] * nm2 + b1h[nt1][1];
        f16x2 t01 = __builtin_elementwise_max(a01 * s01 + c01, zero2);
        f16x2 t23 = __builtin_elementwise_max(a23 * s23 + c23, zero2);
        afu[ks][sl + 0] = __builtin_bit_cast(unsigned, t01);
        afu[ks][sl + 1] = __builtin_bit_cast(unsigned, t23);
    }

    // matmul2 (f16): B from swizzled LDS
    f32x4 acc2[4];
    #pragma unroll
    for (int nt = 0; nt < 4; ++nt)
        acc2[nt] = (f32x4){p2v[nt], p2v[nt], p2v[nt], p2v[nt]};
    #pragma unroll
    for (int ks = 0; ks < 4; ++ks) {
        const unsigned so = ((unsigned)((ks * 4 + g) * 16) ^ xm) >> 2;
        const f16x8 afk = __builtin_bit_cast(f16x8, afu[ks]);
        #pragma unroll
        for (int nt = 0; nt < 4; ++nt) {
            const unsigned idx = (unsigned)(nt * 16 + tl) * 64u + so;
            f16x8 bw = __builtin_bit_cast(f16x8, *(const u32x4*)&sWS[idx]);
            acc2[nt] = __builtin_amdgcn_mfma_f32_16x16x32_f16(afk, bw, acc2[nt], 0, 0, 0);
        }
    }

    // LN2 stats for all q first, then pipelined transpose + store (fma form)
    float vi[4], nvi[4];
    #pragma unroll
    for (int q = 0; q < 4; ++q) {
        float a0 = acc2[0][q], a1 = acc2[1][q], a2 = acc2[2][q], a3 = acc2[3][q];
        float s2 = row16_sum((a0 + a1) + (a2 + a3));
        float q2 = row16_sum((a0 * a0 + a1 * a1) + (a2 * a2 + a3 * a3));
        float m = s2 * (1.f / 64.f);
        vi[q]  = rsqrtf(q2 * (1.f / 64.f) - m * m + 1e-5f);
        nvi[q] = -m * vi[q];
    }
    float* const obase = out + (((long long)(tok0 + tbase) + g * 4) << 6) + 4 * tl;

#define WRQ(q, rr) { \
    float* d = sXp + (rr) * 68; \
    d[ 0 + tl] = acc2[0][q] * vi[q] + nvi[q]; \
    d[16 + tl] = acc2[1][q] * vi[q] + nvi[q]; \
    d[32 + tl] = acc2[2][q] * vi[q] + nvi[q]; \
    d[48 + tl] = acc2[3][q] * vi[q] + nvi[q]; }
#define RDQ(q, rr) { \
    f32x4 w = *(const f32x4*)&sXp[(rr) * 68 + 4 * tl]; \
    f32x4 v; \
    v[0] = w[0] * g2v[0] + b2v[0]; v[1] = w[1] * g2v[1] + b2v[1]; \
    v[2] = w[2] * g2v[2] + b2v[2]; v[3] = w[3] * g2v[3] + b2v[3]; \
    *(f32x4*)(obase + (q) * 64) = v; }
#define RDQG(q, rr) { \
    if (tok0 + tbase + g * 4 + (q) < ntok) RDQ(q, rr) }

    if (full) {
        WRQ(0, 0); WRQ(1, 1); RDQ(0, 0);
        WRQ(2, 0); RDQ(1, 1);
        WRQ(3, 1); RDQ(2, 0); RDQ(3, 1);
    } else {
        WRQ(0, 0); WRQ(1, 1); RDQG(0, 0);
        WRQ(2, 0); RDQG(1, 1);
        WRQ(3, 1); RDQG(2, 0); RDQG(3, 1);
    }
#undef WRQ
#undef RDQ
#undef RDQG
}

// ---------------- main kernel ----------------
__global__ __launch_bounds__(TPB, 1)
void jfe_kernel(
    const float* __restrict__ kp, const float* __restrict__ pkp,
    const unsigned int* __restrict__ ws,
    float* __restrict__ out, int B)
{
    __shared__ __align__(16) unsigned int sWS[SH_U32];   // 17664 B (W2 + params)
    __shared__ __align__(16) unsigned int sA1[2176];     // 8704 B (A1 frags -> sXp)
    __shared__ __align__(16) float4 sPk[TOKPB];
    __shared__ __align__(8)  float2 sQ[TOKPB];
    __shared__ float2 sTc[ROWS];

    const int tid  = threadIdx.x;
    const int lane = tid & 63;
    const int wv   = tid >> 6;
    const int g    = lane >> 4;
    const int tl   = lane & 15;

    const int row0  = blockIdx.x * ROWS;
    const int nrows = min(ROWS, B - row0);
    const long long tok0 = (long long)blockIdx.x * TOKPB;
    const long long ntok = (long long)B * NJ;

    // ---- stage all block-invariant data ws -> LDS ----
    for (int c = tid; c < 1024; c += TPB)
        *(u32x4*)&sWS[c * 4] = *(const u32x4*)&ws[c * 4];
    for (int c = tid; c < 512; c += TPB)
        *(u32x4*)&sA1[c * 4] = *(const u32x4*)&ws[WSU_A1 + c * 4];
    if (tid < 80)
        *(u32x4*)&sWS[SH_G1P + tid * 4] = *(const u32x4*)&ws[WSU_PRM + tid * 4];

    // ---- normalization: 64 tasks spread across all 4 waves ----
    if (tl < 16 && g == 0) {
        const int task  = wv * 16 + tl;
        const int frame = task >> 5;
        const int row   = task & 31;
        if (row < nrows) {
            float ox[NJ], oy[NJ];
            if (frame == 0) {
                const float* rp = kp + (long long)(row0 + row) * 51;
                norm_row(rp, ox, oy);
                #pragma unroll
                for (int j = 0; j < NJ; ++j)
                    sPk[row * NJ + j] = make_float4(ox[j], oy[j], rp[j * 3 + 2], 0.f);
                sTc[row] = make_float2(
                    0.25f * (ox[LSJ] + ox[RSJ] + ox[LHJ] + ox[RHJ]),
                    0.25f * (oy[LSJ] + oy[RSJ] + oy[LHJ] + oy[RHJ]));
            } else {
                norm_row(pkp + (long long)(row0 + row) * 51, ox, oy);
                #pragma unroll
                for (int j = 0; j < NJ; ++j)
                    sQ[row * NJ + j] = make_float2(ox[j], oy[j]);
            }
        }
    }
    __syncthreads();

    // ---- preload per-lane constants from LDS ----
    f16x8 a1f[8];
    #pragma unroll
    for (int nt1 = 0; nt1 < 8; ++nt1)
        a1f[nt1] = __builtin_bit_cast(f16x8,
            *(const u32x4*)&sA1[(nt1 * 64 + lane) * 4]);

    f16x2 g1h[8][2], b1h[8][2];
    #pragma unroll
    for (int nt1 = 0; nt1 < 8; ++nt1) {
        g1h[nt1][0] = __builtin_bit_cast(f16x2, sWS[SH_G1P + (g * 8 + nt1) * 2 + 0]);
        g1h[nt1][1] = __builtin_bit_cast(f16x2, sWS[SH_G1P + (g * 8 + nt1) * 2 + 1]);
        b1h[nt1][0] = __builtin_bit_cast(f16x2, sWS[SH_B1P + (g * 8 + nt1) * 2 + 0]);
        b1h[nt1][1] = __builtin_bit_cast(f16x2, sWS[SH_B1P + (g * 8 + nt1) * 2 + 1]);
    }
    float g2v[4], b2v[4], p2v[4];
    #pragma unroll
    for (int nt = 0; nt < 4; ++nt) {
        g2v[nt] = __builtin_bit_cast(float, sWS[SH_LN2 +   0 + 4 * tl + nt]);
        b2v[nt] = __builtin_bit_cast(float, sWS[SH_LN2 +  64 + 4 * tl + nt]);
        p2v[nt] = __builtin_bit_cast(float, sWS[SH_LN2 + 128 + nt * 16 + tl]);
    }
    __syncthreads();   // all waves' a1f preloads done before sA1 reused as sXp

    float* const sXp = (float*)sA1 + wv * 544 + g * 136;

    const bool full = (nrows == ROWS);
    const int ntiles = (nrows * NJ + 15) >> 4;
    const unsigned xm = (unsigned)tl << 4;

    // ---- 2-stage software pipeline: front(t+4) overlaps back(t) ----
    f32x4 accA[8], accB[8];
    int t = wv;                       // wv < 4 <= ntiles always
    front_tile(t * 16, tl, g, sPk, sQ, sTc, a1f, accA);
    while (true) {
        if (t + 4 < ntiles)
            front_tile((t + 4) * 16, tl, g, sPk, sQ, sTc, a1f, accB);
        back_tile(t * 16, tl, g, xm, tok0, ntok, full, sWS, sXp,
                  g1h, b1h, g2v, b2v, p2v, accA, out);
        t += 4;
        if (t >= ntiles) break;

        if (t + 4 < ntiles)
            front_tile((t + 4) * 16, tl, g, sPk, sQ, sTc, a1f, accA);
        back_tile(t * 16, tl, g, xm, tok0, ntok, full, sWS, sXp,
                  g1h, b1h, g2v, b2v, p2v, accB, out);
        t += 4;
        if (t >= ntiles) break;
    }
}

extern "C" void kernel_launch(void* const* d_in, const int* in_sizes, int n_in,
                              void* d_out, int out_size, void* d_ws, size_t ws_size,
                              hipStream_t stream) {
    const float* kp    = (const float*)d_in[0];
    const float* pkp   = (const float*)d_in[1];
    const float* emb   = (const float*)d_in[2];
    const float* posW  = (const float*)d_in[3];
    const float* posB  = (const float*)d_in[4];
    const float* velW  = (const float*)d_in[5];
    const float* velB  = (const float*)d_in[6];
    const float* angB  = (const float*)d_in[8];
    const float* relW  = (const float*)d_in[9];
    const float* relB  = (const float*)d_in[10];
    const float* confW = (const float*)d_in[11];
    const float* confB = (const float*)d_in[12];
    const float* P1    = (const float*)d_in[13];
    const float* p1b   = (const float*)d_in[14];
    const float* g1    = (const float*)d_in[15];
    const float* b1    = (const float*)d_in[16];
    const float* W2    = (const float*)d_in[17];
    const float* p2b   = (const float*)d_in[18];
    const float* g2    = (const float*)d_in[19];
    const float* b2    = (const float*)d_in[20];
    float* out = (float*)d_out;
    unsigned int* ws = (unsigned int*)d_ws;

    int B = in_sizes[0] / (NJ * 3);

    setup_kernel<<<1, 256, 0, stream>>>(
        emb, posW, posB, velW, velB, angB, relW, relB, confW, confB,
        P1, p1b, g1, b1, W2, p2b, g2, b2, ws);

    int nblocks = (B + ROWS - 1) / ROWS;
    jfe_kernel<<<nblocks, TPB, 0, stream>>>(kp, pkp, ws, out, B);
}

// Round 18
// 57.584 us; speedup vs baseline: 2.0372x; 1.4840x over previous
//
#include <hip/hip_runtime.h>
#include <hip/hip_bf16.h>

#define NJ 17
#define ROWS 32
#define TPB 256
#define TOKPB (ROWS * NJ)   // 544

#define LSJ 5
#define RSJ 6
#define LHJ 11
#define RHJ 12

// ws layout (bytes):
//  [0, 16384)      W2P swizzled f16 image (permuted k-map)
//  [16384, 24576)  A1 f16 fragments [nt1 0..7][lane 0..63][8 halves]
//  [24576, 24832)  g1 packed f16 [g*8+nt1][2] u32
//  [24832, 25088)  b1 packed f16 [g*8+nt1][2] u32
//  [25088, 25856)  f32: g2[64], b2[64], p2b[64]
#define WS_A1   16384
#define WS_G1P  24576
#define WS_B1P  24832
#define WS_LN2  25088
#define WS_U32  6464
#define WS_CHNK 1616

typedef __attribute__((ext_vector_type(8))) short bf16x8;
typedef __attribute__((ext_vector_type(8))) _Float16 f16x8;
typedef __attribute__((ext_vector_type(2))) _Float16 f16x2;
typedef __attribute__((ext_vector_type(4))) float f32x4;
typedef __attribute__((ext_vector_type(4))) unsigned int u32x4;

__device__ __forceinline__ unsigned short f2hu(float x) {
    _Float16 h = (_Float16)x;
    return __builtin_bit_cast(unsigned short, h);
}
// packed f32x2 -> f16x2 (RTZ); builtin returns __fp16 vector, bit-identical
__device__ __forceinline__ f16x2 cvt2h(float lo, float hi) {
    return __builtin_bit_cast(f16x2, __builtin_amdgcn_cvt_pkrtz(lo, hi));
}

// sum-reduce across a 16-lane row via DPP row rotates (VALU pipe, no LDS)
__device__ __forceinline__ float row16_sum(float s) {
    int t;
    t = __builtin_amdgcn_update_dpp(0, __builtin_bit_cast(int, s), 0x121, 0xf, 0xf, true);
    s += __builtin_bit_cast(float, t);
    t = __builtin_amdgcn_update_dpp(0, __builtin_bit_cast(int, s), 0x122, 0xf, 0xf, true);
    s += __builtin_bit_cast(float, t);
    t = __builtin_amdgcn_update_dpp(0, __builtin_bit_cast(int, s), 0x124, 0xf, 0xf, true);
    s += __builtin_bit_cast(float, t);
    t = __builtin_amdgcn_update_dpp(0, __builtin_bit_cast(int, s), 0x128, 0xf, 0xf, true);
    s += __builtin_bit_cast(float, t);
    return s;
}

__device__ __forceinline__ void norm_row(const float* __restrict__ r,
                                         float* __restrict__ ox,
                                         float* __restrict__ oy) {
    float sc0 = r[LSJ*3+2], sc1 = r[RSJ*3+2];
    float hc0 = r[LHJ*3+2], hc1 = r[RHJ*3+2];
    bool ut = ((sc0 > 0.f) || (sc1 > 0.f)) && ((hc0 > 0.f) || (hc1 > 0.f));

    float wl = sc0 > 0.f ? 1.f : 0.f;
    float wr = sc1 > 0.f ? 1.f : 0.f;
    float ws = fmaxf(wl + wr, 1.f);
    float smx = (wl * r[LSJ*3+0] + wr * r[RSJ*3+0]) / ws;
    float smy = (wl * r[LSJ*3+1] + wr * r[RSJ*3+1]) / ws;

    wl = hc0 > 0.f ? 1.f : 0.f;
    wr = hc1 > 0.f ? 1.f : 0.f;
    ws = fmaxf(wl + wr, 1.f);
    float hmx = (wl * r[LHJ*3+0] + wr * r[RHJ*3+0]) / ws;
    float hmy = (wl * r[LHJ*3+1] + wr * r[RHJ*3+1]) / ws;

    if (!ut) { smx = 0.f; smy = 0.f; hmx = 0.f; hmy = 0.f; }

    float cx = (smx + hmx) * 0.5f;
    float cy = (smy + hmy) * 0.5f;
    float dx = smx - hmx, dy = smy - hmy;
    float hh = sqrtf(dx * dx + dy * dy);
    bool valid = ut && (hh >= 10.0f);

    float mnx = r[0], mxx = r[0], mny = r[1], mxy = r[1];
    #pragma unroll
    for (int j = 1; j < NJ; ++j) {
        float x = r[j*3], y = r[j*3+1];
        mnx = fminf(mnx, x); mxx = fmaxf(mxx, x);
        mny = fminf(mny, y); mxy = fmaxf(mxy, y);
    }

    float ih  = 1.f / (hh + 1e-6f);
    float ibx = 1.f / (mxx - mnx + 1e-6f);
    float iby = 1.f / (mxy - mny + 1e-6f);

    #pragma unroll
    for (int j = 0; j < NJ; ++j) {
        float x = r[j*3], y = r[j*3+1];
        float tx = (x - cx) * ih, ty = (y - cy) * ih;
        float bx = (x - mnx) * ibx, by = (y - mny) * iby;
        float nx = valid ? tx : bx;
        float ny = valid ? ty : by;
        ox[j] = fminf(fmaxf(nx, -5.f), 5.f);
        oy[j] = fminf(fmaxf(ny, -5.f), 5.f);
    }
}

// ---------------- setup kernel: fold weights once into ws ----------------
__global__ __launch_bounds__(256) void setup_kernel(
    const float* __restrict__ emb,
    const float* __restrict__ posW, const float* __restrict__ posB,
    const float* __restrict__ velW, const float* __restrict__ velB,
    const float* __restrict__ angB,
    const float* __restrict__ relW, const float* __restrict__ relB,
    const float* __restrict__ confW, const float* __restrict__ confB,
    const float* __restrict__ P1, const float* __restrict__ p1b,
    const float* __restrict__ g1, const float* __restrict__ b1,
    const float* __restrict__ W2, const float* __restrict__ p2b,
    const float* __restrict__ g2, const float* __restrict__ b2,
    unsigned int* __restrict__ ws)
{
    __shared__ float sPA[7][128];
    __shared__ float sBase[128];
    __shared__ float sK0[17][128];
    const int tid = threadIdx.x;

    if (tid < 128) {
        const int n = tid;
        float pa0 = 0.f, pa1 = 0.f;
        #pragma unroll
        for (int i = 0; i < 16; ++i) {
            float w = P1[(16 + i) * 128 + n];
            pa0 += posW[i] * w; pa1 += posW[16 + i] * w;
        }
        float pv0 = 0.f, pv1 = 0.f;
        #pragma unroll
        for (int i = 0; i < 8; ++i) {
            float w = P1[(32 + i) * 128 + n];
            pv0 += velW[i] * w; pv1 += velW[8 + i] * w;
        }
        float pr0 = 0.f, pr1 = 0.f;
        #pragma unroll
        for (int i = 0; i < 8; ++i) {
            float w = P1[(48 + i) * 128 + n];
            pr0 += relW[i] * w; pr1 += relW[8 + i] * w;
        }
        float pc = 0.f;
        #pragma unroll
        for (int i = 0; i < 4; ++i) pc += confW[i] * P1[(56 + i) * 128 + n];

        float base = p1b[n];
        #pragma unroll
        for (int i = 0; i < 16; ++i) base += posB[i]  * P1[(16 + i) * 128 + n];
        #pragma unroll
        for (int i = 0; i < 8; ++i)  base += velB[i]  * P1[(32 + i) * 128 + n];
        #pragma unroll
        for (int i = 0; i < 8; ++i)  base += angB[i]  * P1[(40 + i) * 128 + n];
        #pragma unroll
        for (int i = 0; i < 8; ++i)  base += relB[i]  * P1[(48 + i) * 128 + n];
        #pragma unroll
        for (int i = 0; i < 4; ++i)  base += confB[i] * P1[(56 + i) * 128 + n];

        sPA[0][n] = pa0; sPA[1][n] = pa1;
        sPA[2][n] = pv0; sPA[3][n] = pv1;
        sPA[4][n] = pr0; sPA[5][n] = pr1;
        sPA[6][n] = pc;  sBase[n] = base;
    } else {
        // W2P swizzled f16 image (row = B-col source channel nt*16+tl)
        const int t = tid - 128;
        const int n = t & 63;
        const int gp = (t >> 6) * 2;
        const unsigned xm = (unsigned)(n & 15) << 4;
        #pragma unroll
        for (int dg = 0; dg < 2; ++dg) {
            const int gg = gp + dg;
            #pragma unroll
            for (int ks = 0; ks < 4; ++ks) {
                unsigned int pk[4];
                #pragma unroll
                for (int ep = 0; ep < 4; ++ep) {
                    int e0 = 2 * ep, e1 = 2 * ep + 1;
                    int c0 = 4 * gg + (e0 & 3) + 16 * (2 * ks + (e0 >> 2));
                    int c1 = 4 * gg + (e1 & 3) + 16 * (2 * ks + (e1 >> 2));
                    unsigned lo = f2hu(W2[c0 * 64 + n]);
                    unsigned hi = f2hu(W2[c1 * 64 + n]);
                    pk[ep] = lo | (hi << 16);
                }
                unsigned byte = (unsigned)n * 256u + ((unsigned)((ks * 4 + gg) * 16) ^ xm);
                *(u32x4*)&ws[byte >> 2] = (u32x4){pk[0], pk[1], pk[2], pk[3]};
            }
        }
    }

    // LN param packing (f16 pairs)
    if (tid < 32) {
        const int gg = tid >> 3, nt1 = tid & 7;
        const int c0 = 4 * gg + 16 * nt1;
        ws[(WS_G1P >> 2) + tid * 2 + 0] = (unsigned)f2hu(g1[c0+0]) | ((unsigned)f2hu(g1[c0+1]) << 16);
        ws[(WS_G1P >> 2) + tid * 2 + 1] = (unsigned)f2hu(g1[c0+2]) | ((unsigned)f2hu(g1[c0+3]) << 16);
        ws[(WS_B1P >> 2) + tid * 2 + 0] = (unsigned)f2hu(b1[c0+0]) | ((unsigned)f2hu(b1[c0+1]) << 16);
        ws[(WS_B1P >> 2) + tid * 2 + 1] = (unsigned)f2hu(b1[c0+2]) | ((unsigned)f2hu(b1[c0+3]) << 16);
    } else if (tid >= 64 && tid < 256) {
        const int i = tid - 64;   // 0..191
        float v = (i < 64) ? g2[i] : (i < 128 ? b2[i - 64] : p2b[i - 128]);
        ws[(WS_LN2 >> 2) + i] = __builtin_bit_cast(unsigned, v);
    }
    __syncthreads();

    // K0 table
    for (int e = tid; e < NJ * 128; e += 256) {
        int j = e >> 7, n = e & 127;
        float v = sBase[n];
        #pragma unroll
        for (int t = 0; t < 16; ++t) v += emb[j * 16 + t] * P1[t * 128 + n];
        sK0[j][n] = v;
    }
    __syncthreads();

    // A1 f16 fragments
    for (int i = tid; i < 512; i += 256) {
        const int nt1 = i >> 6, ln = i & 63, gg = ln >> 4, tl2 = ln & 15;
        const int ch = tl2 + 16 * nt1;
        float w[8];
        #pragma unroll
        for (int e = 0; e < 8; ++e) w[e] = 0.f;
        if (gg == 0) {
            #pragma unroll
            for (int e = 0; e < 7; ++e) w[e] = sPA[e][ch];
            w[7] = sK0[0][ch];
        } else if (gg == 1) {
            #pragma unroll
            for (int e = 0; e < 8; ++e) w[e] = sK0[e + 1][ch];
        } else if (gg == 2) {
            #pragma unroll
            for (int e = 0; e < 8; ++e) w[e] = sK0[e + 9][ch];
        }
        unsigned u[4];
        #pragma unroll
        for (int p = 0; p < 4; ++p) {
            unsigned short lo = f2hu(w[2*p]);
            unsigned short hi = f2hu(w[2*p+1]);
            u[p] = (unsigned)lo | ((unsigned)hi << 16);
        }
        *(u32x4*)&ws[(WS_A1 >> 2) + i * 4] = (u32x4){u[0], u[1], u[2], u[3]};
    }
}

// ---------------- main kernel ----------------
__global__ __launch_bounds__(TPB, 2)
void jfe_kernel(
    const float* __restrict__ kp, const float* __restrict__ pkp,
    const unsigned int* __restrict__ ws,
    float* __restrict__ out, int B)
{
    __shared__ __align__(16) unsigned int sWS[WS_U32];   // 25856 B
    __shared__ __align__(16) float4 sPk[TOKPB];
    __shared__ __align__(8)  float2 sQ[TOKPB];
    __shared__ float2 sTc[ROWS];
    __shared__ __align__(16) float sXp[4][4][80];        // stride 80: 2-way banks max

    const int tid  = threadIdx.x;
    const int lane = tid & 63;
    const int wv   = tid >> 6;
    const int g    = lane >> 4;
    const int tl   = lane & 15;

    const int row0  = blockIdx.x * ROWS;
    const int nrows = min(ROWS, B - row0);
    const long long tok0 = (long long)blockIdx.x * TOKPB;
    const long long ntok = (long long)B * NJ;

    // ---- stage all block-invariant data ws -> LDS (linear u32x4 copy) ----
    for (int c = tid; c < WS_CHNK; c += TPB) {
        u32x4 t = *(const u32x4*)&ws[c * 4];
        *(u32x4*)&sWS[c * 4] = t;
    }

    // ---- normalization: 64 tasks spread across all 4 waves ----
    if (tl < 16 && g == 0) {
        const int task  = wv * 16 + tl;
        const int frame = task >> 5;
        const int row   = task & 31;
        if (row < nrows) {
            float ox[NJ], oy[NJ];
            if (frame == 0) {
                const float* rp = kp + (long long)(row0 + row) * 51;
                norm_row(rp, ox, oy);
                #pragma unroll
                for (int j = 0; j < NJ; ++j)
                    sPk[row * NJ + j] = make_float4(ox[j], oy[j], rp[j * 3 + 2], 0.f);
                sTc[row] = make_float2(
                    0.25f * (ox[LSJ] + ox[RSJ] + ox[LHJ] + ox[RHJ]),
                    0.25f * (oy[LSJ] + oy[RSJ] + oy[LHJ] + oy[RHJ]));
            } else {
                norm_row(pkp + (long long)(row0 + row) * 51, ox, oy);
                #pragma unroll
                for (int j = 0; j < NJ; ++j)
                    sQ[row * NJ + j] = make_float2(ox[j], oy[j]);
            }
        }
    }
    __syncthreads();

    // ---- preload per-lane constants from LDS ----
    f16x8 a1f[8];
    #pragma unroll
    for (int nt1 = 0; nt1 < 8; ++nt1)
        a1f[nt1] = __builtin_bit_cast(f16x8,
            *(const u32x4*)&sWS[(WS_A1 >> 2) + (nt1 * 64 + lane) * 4]);

    f16x2 g1h[8][2], b1h[8][2];
    #pragma unroll
    for (int nt1 = 0; nt1 < 8; ++nt1) {
        g1h[nt1][0] = __builtin_bit_cast(f16x2, sWS[(WS_G1P >> 2) + (g * 8 + nt1) * 2 + 0]);
        g1h[nt1][1] = __builtin_bit_cast(f16x2, sWS[(WS_G1P >> 2) + (g * 8 + nt1) * 2 + 1]);
        b1h[nt1][0] = __builtin_bit_cast(f16x2, sWS[(WS_B1P >> 2) + (g * 8 + nt1) * 2 + 0]);
        b1h[nt1][1] = __builtin_bit_cast(f16x2, sWS[(WS_B1P >> 2) + (g * 8 + nt1) * 2 + 1]);
    }
    // p2b indexed by SOURCE channel (nt*16+tl); g2/b2 by TARGET channel (4*tl+i)
    float g2v[4], b2v[4], p2v[4];
    #pragma unroll
    for (int nt = 0; nt < 4; ++nt) {
        g2v[nt] = __builtin_bit_cast(float, sWS[(WS_LN2 >> 2) +   0 + 4 * tl + nt]);
        b2v[nt] = __builtin_bit_cast(float, sWS[(WS_LN2 >> 2) +  64 + 4 * tl + nt]);
        p2v[nt] = __builtin_bit_cast(float, sWS[(WS_LN2 >> 2) + 128 + nt * 16 + tl]);
    }

    // ---- main loop: tiles strided across waves ----
    const int ntiles = (nrows * NJ + 15) >> 4;
    const unsigned xm = (unsigned)tl << 4;
    #pragma unroll 1
    for (int t = wv; t < ntiles; t += 4) {
        const int tbase = t * 16;
        const int tok = tbase + tl;
        const int r = (tok * 3856) >> 16;      // tok/17 for tok<4096
        const int j = tok - r * NJ;

        const float4 pk = sPk[tok];
        const float2 qv = sQ[tok];
        const float2 tc = sTc[r];
        const float px = pk.x, py = pk.y, cf = pk.z;
        const float vx = px - qv.x, vy = py - qv.y;
        const float rx = px - tc.x, ry = py - tc.y;

        // B1 fragment: token tl's features along k1 = g*8+e
        f16x8 bf;
        {
            const int base7 = g * 8 - 7;
            #pragma unroll
            for (int e = 0; e < 8; ++e) {
                float oh = ((base7 + e) == j) ? 1.f : 0.f;
                float val;
                if (e == 0) val = (g == 0) ? px : oh;
                else if (e == 1) val = (g == 0) ? py : oh;
                else if (e == 2) val = (g == 0) ? vx : oh;
                else if (e == 3) val = (g == 0) ? vy : oh;
                else if (e == 4) val = (g == 0) ? rx : oh;
                else if (e == 5) val = (g == 0) ? ry : oh;
                else if (e == 6) val = (g == 0) ? cf : oh;
                else val = oh;
                bf[e] = (_Float16)val;
            }
        }

        // matmul1 (swapped): lane holds tok=tl, ch = 4g+q+16nt1
        f32x4 acc1[8];
        #pragma unroll
        for (int nt1 = 0; nt1 < 8; ++nt1)
            acc1[nt1] = __builtin_amdgcn_mfma_f32_16x16x32_f16(
                a1f[nt1], bf, (f32x4){0.f, 0.f, 0.f, 0.f}, 0, 0, 0);

        // LN1 over 128 channels (4 lanes xor16/32 share token tl)
        float s = 0.f, ss = 0.f;
        #pragma unroll
        for (int nt1 = 0; nt1 < 8; ++nt1)
            #pragma unroll
            for (int q = 0; q < 4; ++q) { float v = acc1[nt1][q]; s += v; ss += v * v; }
        s += __shfl_xor(s, 16); ss += __shfl_xor(ss, 16);
        s += __shfl_xor(s, 32); ss += __shfl_xor(ss, 32);
        const float mu  = s * (1.f / 128.f);
        const float inv = rsqrtf(ss * (1.f / 128.f) - mu * mu + 1e-5f);

        // LN1 apply + relu in PACKED f16: t = max(a*(inv*g) + (b - mu*inv*g), 0)
        const f16x2 im2 = cvt2h(inv, inv);
        const f16x2 nm2 = cvt2h(-mu * inv, -mu * inv);
        const f16x2 zero2 = (f16x2)(_Float16)0.f;
        u32x4 afu[4];
        #pragma unroll
        for (int nt1 = 0; nt1 < 8; ++nt1) {
            const int ks = nt1 >> 1, sl = 2 * (nt1 & 1);
            f16x2 a01 = cvt2h(acc1[nt1][0], acc1[nt1][1]);
            f16x2 a23 = cvt2h(acc1[nt1][2], acc1[nt1][3]);
            f16x2 s01 = g1h[nt1][0] * im2;
            f16x2 s23 = g1h[nt1][1] * im2;
            f16x2 c01 = g1h[nt1][0] * nm2 + b1h[nt1][0];
            f16x2 c23 = g1h[nt1][1] * nm2 + b1h[nt1][1];
            f16x2 t01 = __builtin_elementwise_max(a01 * s01 + c01, zero2);
            f16x2 t23 = __builtin_elementwise_max(a23 * s23 + c23, zero2);
            afu[ks][sl + 0] = __builtin_bit_cast(unsigned, t01);
            afu[ks][sl + 1] = __builtin_bit_cast(unsigned, t23);
        }

        // matmul2 (f16): B from swizzled LDS (tile nt, col tl = channel nt*16+tl)
        f32x4 acc2[4];
        #pragma unroll
        for (int nt = 0; nt < 4; ++nt)
            acc2[nt] = (f32x4){p2v[nt], p2v[nt], p2v[nt], p2v[nt]};
        #pragma unroll
        for (int ks = 0; ks < 4; ++ks) {
            const unsigned so = ((unsigned)((ks * 4 + g) * 16) ^ xm) >> 2;
            const f16x8 afk = __builtin_bit_cast(f16x8, afu[ks]);
            #pragma unroll
            for (int nt = 0; nt < 4; ++nt) {
                const unsigned idx = (unsigned)(nt * 16 + tl) * 64u + so;
                f16x8 bw = __builtin_bit_cast(f16x8, *(const u32x4*)&sWS[idx]);
                acc2[nt] = __builtin_amdgcn_mfma_f32_16x16x32_f16(afk, bw, acc2[nt], 0, 0, 0);
            }
        }

        // LN2 (f32 stats) + per-wave LDS transpose + full-line f32x4 store
        const long long gbase = tok0 + tbase;
        #pragma unroll
        for (int q = 0; q < 4; ++q) {
            float a0 = acc2[0][q], a1 = acc2[1][q], a2 = acc2[2][q], a3 = acc2[3][q];
            float s2 = row16_sum(a0 + a1 + a2 + a3);
            float q2 = row16_sum(a0*a0 + a1*a1 + a2*a2 + a3*a3);
            const long long gtok = gbase + g * 4 + q;
            const float mu2  = s2 * (1.f / 64.f);
            const float inv2 = rsqrtf(q2 * (1.f / 64.f) - mu2 * mu2 + 1e-5f);
            sXp[wv][g][ 0 + tl] = (a0 - mu2) * inv2;
            sXp[wv][g][16 + tl] = (a1 - mu2) * inv2;
            sXp[wv][g][32 + tl] = (a2 - mu2) * inv2;
            sXp[wv][g][48 + tl] = (a3 - mu2) * inv2;
            f32x4 w = *(const f32x4*)&sXp[wv][g][4 * tl];
            if (gtok < ntok) {
                f32x4 v;
                v[0] = w[0] * g2v[0] + b2v[0];
                v[1] = w[1] * g2v[1] + b2v[1];
                v[2] = w[2] * g2v[2] + b2v[2];
                v[3] = w[3] * g2v[3] + b2v[3];
                *(f32x4*)(out + gtok * 64 + 4 * tl) = v;
            }
        }
    }
}

extern "C" void kernel_launch(void* const* d_in, const int* in_sizes, int n_in,
                              void* d_out, int out_size, void* d_ws, size_t ws_size,
                              hipStream_t stream) {
    const float* kp    = (const float*)d_in[0];
    const float* pkp   = (const float*)d_in[1];
    const float* emb   = (const float*)d_in[2];
    const float* posW  = (const float*)d_in[3];
    const float* posB  = (const float*)d_in[4];
    const float* velW  = (const float*)d_in[5];
    const float* velB  = (const float*)d_in[6];
    const float* angB  = (const float*)d_in[8];
    const float* relW  = (const float*)d_in[9];
    const float* relB  = (const float*)d_in[10];
    const float* confW = (const float*)d_in[11];
    const float* confB = (const float*)d_in[12];
    const float* P1    = (const float*)d_in[13];
    const float* p1b   = (const float*)d_in[14];
    const float* g1    = (const float*)d_in[15];
    const float* b1    = (const float*)d_in[16];
    const float* W2    = (const float*)d_in[17];
    const float* p2b   = (const float*)d_in[18];
    const float* g2    = (const float*)d_in[19];
    const float* b2    = (const float*)d_in[20];
    float* out = (float*)d_out;
    unsigned int* ws = (unsigned int*)d_ws;

    int B = in_sizes[0] / (NJ * 3);

    setup_kernel<<<1, 256, 0, stream>>>(
        emb, posW, posB, velW, velB, angB, relW, relB, confW, confB,
        P1, p1b, g1, b1, W2, p2b, g2, b2, ws);

    int nblocks = (B + ROWS - 1) / ROWS;
    jfe_kernel<<<nblocks, TPB, 0, stream>>>(kp, pkp, ws, out, B);
}